// Round 14
// baseline (2913.445 us; speedup 1.0000x reference)
//
#include <hip/hip_runtime.h>
#include <hip/hip_bf16.h>

#define S_LEN 2048
#define HIDN  4096
#define NH    32
#define HD    128

typedef __attribute__((ext_vector_type(8))) __bf16 bf16x8;
typedef __attribute__((ext_vector_type(4))) float  f32x4;
typedef unsigned short u16;

__device__ __forceinline__ float bf2f(u16 u) {
  unsigned v = ((unsigned)u) << 16;
  return __builtin_bit_cast(float, v);
}
__device__ __forceinline__ u16 f2bf(float f) {
  unsigned u = __builtin_bit_cast(unsigned, f);
  u += 0x7FFFu + ((u >> 16) & 1u);
  return (u16)(u >> 16);
}
__device__ __forceinline__ float fexp2(float x) {   // 2^x, single v_exp_f32
  float r; asm("v_exp_f32 %0, %1" : "=v"(r) : "v"(x)); return r;
}
__device__ __forceinline__ void gload16(const void* g, void* l) {
  __builtin_amdgcn_global_load_lds((const __attribute__((address_space(1))) void*)g,
                                   (__attribute__((address_space(3))) void*)l, 16, 0, 0);
}
#define MFMA16(a, b, c) __builtin_amdgcn_mfma_f32_16x16x32_bf16(a, b, c, 0, 0, 0)

// ---------------- prep kernels ----------------

// f32 [R][C] -> bf16 [C][R]
__global__ void transpose_cast(const float* __restrict__ in, u16* __restrict__ out,
                               int R, int C) {
  __shared__ float t[32][33];
  const int c0 = blockIdx.x * 32, r0 = blockIdx.y * 32;
  const int tx = threadIdx.x, ty = threadIdx.y;
#pragma unroll
  for (int i = 0; i < 4; ++i)
    t[ty + i * 8][tx] = in[(size_t)(r0 + ty + i * 8) * C + c0 + tx];
  __syncthreads();
#pragma unroll
  for (int i = 0; i < 4; ++i)
    out[(size_t)(c0 + ty + i * 8) * R + r0 + tx] = f2bf(t[tx][ty + i * 8]);
}

struct u16x4s { u16 x, y, z, w; };

__global__ void cast_bf16_k(const float* __restrict__ in, u16* __restrict__ out, int n4) {
  int i = blockIdx.x * 256 + threadIdx.x;
  if (i < n4) {
    float4 v = ((const float4*)in)[i];
    u16x4s o;
    o.x = f2bf(v.x); o.y = f2bf(v.y); o.z = f2bf(v.z); o.w = f2bf(v.w);
    ((u16x4s*)out)[i] = o;
  }
}

__global__ void rope_table_k(const int* __restrict__ pos, float* __restrict__ cs,
                             float* __restrict__ sn) {
  int idx = blockIdx.x * 256 + threadIdx.x;   // S_LEN*64 total
  int s = idx >> 6, d = idx & 63;
  float inv = exp2f((-(float)d / 64.f) * 13.287712379549449f); // log2(10000)
  float ang = (float)pos[s] * inv;
  cs[idx] = cosf(ang);
  sn[idx] = sinf(ang);
}

// ---------------- 256x256 4-phase GEMM, read-one-phase-ahead ----------------
// C[M][N] = A[M][K] * Bt[N][K]^T (+bias). 512 threads = 8 waves (2M x 4N),
// per-wave 128x64. BK=64; LDS 128 KiB, XOR-slot swizzled; bm-fastest swizzle.
// NEW: every MFMA cluster consumes registers ds_read >=1 phase (2 barriers)
// earlier -> post-barrier lgkmcnt stall removed:
//  ph1: STG B0(t+1); read ahi(t)        | bar | q1: alo x b01 | bar
//  ph2: STG B1(t+1); read b23(t)        | bar | q2: ahi x b01 | bar
//  ph3: STG A0(t+2)                     | bar | q3: alo x b23 | bar
//  ph4: STG A1(t+2); vmcnt(4) [=> tile t+1 fully landed: only A(t+2) remains
//       outstanding]; read alo(t+1),b01(t+1) from buf^1 | bar | q4 | bar
// Ping-pong register sets (A/B) via 2x unroll; NT even.
// Region audit (vs proven R5 slots, unchanged): A-half readers end ph1(ahi)/
// ph4(t-1)(alo) -> staged ph3/ph4; B0 reader b01 reads ph4(t-1), staged
// ph1(t+1) into other buffer; B1 reader b23 reads ph2, staged ph2(t).
// EPI=0: f32 out. EPI=1: fused QKV epilogue (rope Q/K + V-transpose) via
// slot-swizzled LDS tile (R13-proven).
template <int EPI>
__global__ __launch_bounds__(512) void gemm256(
    const u16* __restrict__ A, const u16* __restrict__ Bt,
    const float* __restrict__ bias, void* __restrict__ Cv,
    int M, int N, int K, int nbm,
    u16* __restrict__ Qo, u16* __restrict__ Ko, u16* __restrict__ Vo,
    const float* __restrict__ cs, const float* __restrict__ sn) {
  __shared__ alignas(16) u16 lds[2][2][2][128 * 64];
  const int tid = threadIdx.x;
  const int cpx = gridDim.x >> 3;
  const int swz = (blockIdx.x & 7) * cpx + (blockIdx.x >> 3);   // bijective (nb%8==0)
  const int bm = (swz % nbm) * 256, bn = (swz / nbm) * 256;     // bm fastest: B reuse in L2
  const int w = tid >> 6, l = tid & 63;
  const int wm = w >> 2, wn = w & 3;
  const int lr = l & 15, lg = l >> 4;
  const int rswz = (lr & 7) * 8;                  // read-side XOR (u16 units)
  const int rl = tid >> 3;                        // staging row (per 8 threads)
  const int sl = (tid & 7) ^ ((tid >> 3) & 7);    // staging source slot (inverse swz)
  const int brow = (wn & 1) * 64;
  const u16* Ap = A + (size_t)bm * K;
  const u16* Bp = Bt + (size_t)bn * K;

#define STG(buf, ab, half, kt) do { \
    const u16* s_ = (ab ? Bp : Ap) + (size_t)((half) * 128 + rl) * K + (kt) * 64 + sl * 8; \
    u16* d_ = &lds[buf][ab][half][tid * 8]; \
    gload16(s_, d_); \
    gload16(s_ + (size_t)64 * K, d_ + 4096); \
  } while (0)

  f32x4 acc[8][4] = {};
  const int NT = K >> 6;
  bf16x8 aloA[4][2], b01A[2][2], aloB[4][2], b01B[2][2];
  bf16x8 ahi[4][2], b23[2][2];

  // prologue: tile 0 complete (8 loads) + A halves of tile 1 (4 loads)
  STG(0, 0, 0, 0); STG(0, 0, 1, 0); STG(0, 1, 0, 0); STG(0, 1, 1, 0);
  STG(1, 0, 0, 1); STG(1, 0, 1, 1);
  asm volatile("s_waitcnt vmcnt(4)" ::: "memory");   // tile 0 landed
  __builtin_amdgcn_s_barrier();
  {
    const u16* pA = &lds[0][0][wm][0];
    const u16* pB = &lds[0][1][wn >> 1][0];
#pragma unroll
    for (int mi = 0; mi < 4; ++mi)
#pragma unroll
      for (int ks = 0; ks < 2; ++ks)
        aloA[mi][ks] = *(const bf16x8*)&pA[(mi * 16 + lr) * 64 + ((ks * 32 + lg * 8) ^ rswz)];
#pragma unroll
    for (int ni = 0; ni < 2; ++ni)
#pragma unroll
      for (int ks = 0; ks < 2; ++ks)
        b01A[ni][ks] = *(const bf16x8*)&pB[(brow + ni * 16 + lr) * 64 + ((ks * 32 + lg * 8) ^ rswz)];
  }

#define KBODY(AL, B01, ALN, B01N, t) do { \
    const int buf_ = (t) & 1; \
    const u16* pA_ = &lds[buf_][0][wm][0]; \
    const u16* pB_ = &lds[buf_][1][wn >> 1][0]; \
    const u16* pAN_ = &lds[buf_ ^ 1][0][wm][0]; \
    const u16* pBN_ = &lds[buf_ ^ 1][1][wn >> 1][0]; \
    /* ---- phase 1 ---- */ \
    if ((t) + 1 < NT) STG(buf_ ^ 1, 1, 0, (t) + 1); \
    _Pragma("unroll") for (int mi = 0; mi < 4; ++mi) \
      _Pragma("unroll") for (int ks = 0; ks < 2; ++ks) \
        ahi[mi][ks] = *(const bf16x8*)&pA_[((mi + 4) * 16 + lr) * 64 + ((ks * 32 + lg * 8) ^ rswz)]; \
    __builtin_amdgcn_s_barrier(); \
    __builtin_amdgcn_s_setprio(1); \
    _Pragma("unroll") for (int mi = 0; mi < 4; ++mi) \
      _Pragma("unroll") for (int ni = 0; ni < 2; ++ni) \
        _Pragma("unroll") for (int ks = 0; ks < 2; ++ks) \
          acc[mi][ni] = MFMA16(AL[mi][ks], B01[ni][ks], acc[mi][ni]); \
    __builtin_amdgcn_s_setprio(0); \
    __builtin_amdgcn_s_barrier(); \
    /* ---- phase 2 ---- */ \
    if ((t) + 1 < NT) STG(buf_ ^ 1, 1, 1, (t) + 1); \
    _Pragma("unroll") for (int ni = 0; ni < 2; ++ni) \
      _Pragma("unroll") for (int ks = 0; ks < 2; ++ks) \
        b23[ni][ks] = *(const bf16x8*)&pB_[(brow + (ni + 2) * 16 + lr) * 64 + ((ks * 32 + lg * 8) ^ rswz)]; \
    __builtin_amdgcn_s_barrier(); \
    __builtin_amdgcn_s_setprio(1); \
    _Pragma("unroll") for (int mi = 0; mi < 4; ++mi) \
      _Pragma("unroll") for (int ni = 0; ni < 2; ++ni) \
        _Pragma("unroll") for (int ks = 0; ks < 2; ++ks) \
          acc[mi + 4][ni] = MFMA16(ahi[mi][ks], B01[ni][ks], acc[mi + 4][ni]); \
    __builtin_amdgcn_s_setprio(0); \
    __builtin_amdgcn_s_barrier(); \
    /* ---- phase 3 ---- */ \
    if ((t) + 2 < NT) STG(buf_, 0, 0, (t) + 2); \
    __builtin_amdgcn_s_barrier(); \
    __builtin_amdgcn_s_setprio(1); \
    _Pragma("unroll") for (int mi = 0; mi < 4; ++mi) \
      _Pragma("unroll") for (int ni = 0; ni < 2; ++ni) \
        _Pragma("unroll") for (int ks = 0; ks < 2; ++ks) \
          acc[mi][ni + 2] = MFMA16(AL[mi][ks], b23[ni][ks], acc[mi][ni + 2]); \
    __builtin_amdgcn_s_setprio(0); \
    __builtin_amdgcn_s_barrier(); \
    /* ---- phase 4 ---- */ \
    if ((t) + 2 < NT) STG(buf_, 0, 1, (t) + 2); \
    if ((t) + 1 < NT) { \
      if ((t) + 2 < NT) asm volatile("s_waitcnt vmcnt(4)" ::: "memory"); \
      else              asm volatile("s_waitcnt vmcnt(0)" ::: "memory"); \
      _Pragma("unroll") for (int mi = 0; mi < 4; ++mi) \
        _Pragma("unroll") for (int ks = 0; ks < 2; ++ks) \
          ALN[mi][ks] = *(const bf16x8*)&pAN_[(mi * 16 + lr) * 64 + ((ks * 32 + lg * 8) ^ rswz)]; \
      _Pragma("unroll") for (int ni = 0; ni < 2; ++ni) \
        _Pragma("unroll") for (int ks = 0; ks < 2; ++ks) \
          B01N[ni][ks] = *(const bf16x8*)&pBN_[(brow + ni * 16 + lr) * 64 + ((ks * 32 + lg * 8) ^ rswz)]; \
    } else { \
      asm volatile("s_waitcnt vmcnt(0)" ::: "memory"); \
    } \
    __builtin_amdgcn_s_barrier(); \
    __builtin_amdgcn_s_setprio(1); \
    _Pragma("unroll") for (int mi = 0; mi < 4; ++mi) \
      _Pragma("unroll") for (int ni = 0; ni < 2; ++ni) \
        _Pragma("unroll") for (int ks = 0; ks < 2; ++ks) \
          acc[mi + 4][ni + 2] = MFMA16(ahi[mi][ks], b23[ni][ks], acc[mi + 4][ni + 2]); \
    __builtin_amdgcn_s_setprio(0); \
    __builtin_amdgcn_s_barrier(); \
  } while (0)

  for (int t = 0; t < NT; t += 2) {
    KBODY(aloA, b01A, aloB, b01B, t);
    KBODY(aloB, b01B, aloA, b01A, t + 1);
  }
#undef KBODY
#undef STG

  if (EPI == 0) {
#pragma unroll
    for (int ni = 0; ni < 4; ++ni) {
      const int col = bn + wn * 64 + ni * 16 + lr;
      const float bv = bias[col];
#pragma unroll
      for (int mi = 0; mi < 8; ++mi) {
        const int row = bm + wm * 128 + mi * 16 + lg * 4;
#pragma unroll
        for (int r = 0; r < 4; ++r)
          ((float*)Cv)[(size_t)(row + r) * N + col] = acc[mi][ni][r] + bv;
      }
    }
  } else {
    // ---- fused QKV epilogue (slot-swizzled tile) ----
    u16* tile = (u16*)lds;          // 256x256 bf16 = 128 KiB (K-loop buffers dead)
    const int cr = lg * 4, cc = lr;
#pragma unroll
    for (int ni = 0; ni < 4; ++ni) {
      const int lcol = wn * 64 + ni * 16 + cc;
      const float bv = bias[bn + lcol];
#pragma unroll
      for (int mi = 0; mi < 8; ++mi) {
        const int lrow = wm * 128 + mi * 16 + cr;
#pragma unroll
        for (int r = 0; r < 4; ++r) {
          const int rw = lrow + r;
          tile[rw * 256 + ((((lcol >> 3) ^ (rw & 7)) << 3) | (lcol & 7))] =
              f2bf(acc[mi][ni][r] + bv);
        }
      }
    }
    __syncthreads();
    if (bn < 2 * HIDN) {
      // Q or K tile: rope pairs (d, d+64) same-thread via LDS
      const float sc = (bn < HIDN) ? 0.12751743f : 1.0f;  // (1/sqrt(128))*log2e in Q
      u16* dst0 = (bn < HIDN) ? Qo : Ko;
      const int hbase = (bn & (HIDN - 1)) >> 7;
#pragma unroll
      for (int it = 0; it < 8; ++it) {
        const int idx = it * 512 + tid;                   // 2 heads*256 s*8 chunks
        const int hh = idx >> 11, slc = (idx >> 3) & 255, d0 = (idx & 7) * 8;
        const int colA = hh * 128 + d0, colB = colA + 64;
        const bf16x8 va = *(const bf16x8*)&tile[slc * 256 + (((colA >> 3) ^ (slc & 7)) << 3)];
        const bf16x8 vb = *(const bf16x8*)&tile[slc * 256 + (((colB >> 3) ^ (slc & 7)) << 3)];
        const int sg = bm + slc, b_ = sg >> 11, s_ = sg & 2047;
        const float4 c0 = *(const float4*)&cs[s_ * 64 + d0];
        const float4 c1 = *(const float4*)&cs[s_ * 64 + d0 + 4];
        const float4 s0v = *(const float4*)&sn[s_ * 64 + d0];
        const float4 s1v = *(const float4*)&sn[s_ * 64 + d0 + 4];
        bf16x8 r1, r2;
#pragma unroll
        for (int j = 0; j < 8; ++j) {
          float x1 = (float)va[j], x2 = (float)vb[j];
          float cj = (j < 4) ? c0[j & 3] : c1[j & 3];
          float sj = (j < 4) ? s0v[j & 3] : s1v[j & 3];
          r1[j] = (__bf16)((x1 * cj - x2 * sj) * sc);
          r2[j] = (__bf16)((x2 * cj + x1 * sj) * sc);
        }
        u16* dp = dst0 + ((size_t)(b_ * NH + hbase + hh) * S_LEN + s_) * HD + d0;
        *(bf16x8*)dp = r1;
        *(bf16x8*)(dp + 64) = r2;
      }
    } else {
      // V tile: transpose to Vt[B,H,D,S]
      const int hbase = (bn - 2 * HIDN) >> 7;
#pragma unroll
      for (int it = 0; it < 16; ++it) {
        const int idx = it * 512 + tid;                   // 32 s-chunks * 256 cols
        const int sc8 = idx >> 8, cl = idx & 255;
        const int s0 = sc8 * 8;
        bf16x8 v;
#pragma unroll
        for (int j = 0; j < 8; ++j) {
          const int rw = s0 + j;
          v[j] = __builtin_bit_cast(__bf16,
                 tile[rw * 256 + ((((cl >> 3) ^ (rw & 7)) << 3) | (cl & 7))]);
        }
        const int sg = bm + s0, b_ = sg >> 11, s_ = sg & 2047;
        const int h_ = hbase + (cl >> 7), d_ = cl & 127;
        *(bf16x8*)&Vo[((size_t)(b_ * NH + h_) * HD + d_) * S_LEN + s_] = v;
      }
    }
  }
}

// ---------------- causal flash attention: 8 waves/block, QBLK=128 (R13) ----------
__global__ __launch_bounds__(512) void attn_k(
    const u16* __restrict__ Q, const u16* __restrict__ K,
    const u16* __restrict__ Vt, u16* __restrict__ O) {
  __shared__ alignas(16) u16 kbuf[2][64 * 128];
  __shared__ alignas(16) u16 vbuf[2][128 * 64];
  __shared__ alignas(16) u16 plds[8][16 * 64];
  const int blk = blockIdx.x;
  const int qb = 15 - (blk >> 6);          // longest blocks dispatch first
  const int bhid = blk & 63;
  const int b = bhid >> 5, h = bhid & 31;
  const int tid = threadIdx.x;
  const int w = tid >> 6, l = tid & 63;
  const int lr = l & 15, lg = l >> 4;
  const size_t bh = (size_t)(b * NH + h);
  const u16* Qp = Q + (bh * S_LEN + (size_t)qb * 128 + (size_t)w * 16) * HD;
  const u16* Kp = K + bh * S_LEN * HD;
  const u16* Vp = Vt + bh * HD * S_LEN;

  bf16x8 qf[4];
#pragma unroll
  for (int kd = 0; kd < 4; ++kd)
    qf[kd] = *(const bf16x8*)&Qp[lr * HD + kd * 32 + lg * 8];

  f32x4 oacc[8] = {};
  float m[4], lsum[4];
#pragma unroll
  for (int r = 0; r < 4; ++r) { m[r] = -1e30f; lsum[r] = 0.f; }
  const int nsteps = 2 * qb + 2;
  const int qmin = qb * 128 + w * 16;      // wave-uniform first q row
  const int qmaxw = qmin + 15;
  const int qrow0 = qmin + lg * 4;

#define ASTAGE(buf, kv0) do { \
    _Pragma("unroll") \
    for (int c = 0; c < 2; ++c) { \
      const int kr = c * 32 + (tid >> 4); \
      const int kc = ((tid & 15) * 8) ^ ((kr & 7) << 3); \
      gload16(Kp + (size_t)((kv0) + kr) * HD + kc, &kbuf[buf][c * 4096 + tid * 8]); \
      const int vr = c * 64 + (tid >> 3); \
      const int vc = ((tid & 7) * 8) ^ ((vr & 7) << 3); \
      gload16(Vp + (size_t)vr * S_LEN + (kv0) + vc, &vbuf[buf][c * 4096 + tid * 8]); \
    } \
  } while (0)

  ASTAGE(0, 0);
  for (int st = 0; st < nsteps; ++st) {
    const int kv0 = st * 64;
    const int cur = st & 1;
    __syncthreads();                       // stage(cur) landed; buf cur^1 free
    if (st + 1 < nsteps) ASTAGE(cur ^ 1, kv0 + 64);

    if (kv0 <= qmaxw) {                    // wave-uniform: skip fully-masked steps
      const int na0 = ((qmaxw - kv0) >> 4) + 1;
      const int na = na0 > 4 ? 4 : na0;    // active 16-col n-blocks (wave-uniform)

      // ---- QK^T (active n-blocks only) ----
      f32x4 sacc[4] = {};
      __builtin_amdgcn_s_setprio(1);
#pragma unroll
      for (int n = 0; n < 4; ++n) {
        if (n < na) {
          const int krow = n * 16 + lr;
          const int swzk = (krow & 7) << 3;
#pragma unroll
          for (int kd = 0; kd < 4; ++kd) {
            const bf16x8 kf = *(const bf16x8*)&kbuf[cur][krow * 128 + ((kd * 32 + lg * 8) ^ swzk)];
            sacc[n] = MFMA16(qf[kd], kf, sacc[n]);
          }
        }
      }
      __builtin_amdgcn_s_setprio(0);
      // ---- causal mask (skip when step fully below diagonal) ----
      float sv[4][4];
      if (kv0 + 63 <= qmin) {
#pragma unroll
        for (int n = 0; n < 4; ++n)
#pragma unroll
          for (int r = 0; r < 4; ++r) sv[n][r] = sacc[n][r];
      } else {
#pragma unroll
        for (int n = 0; n < 4; ++n) {
          const int col = kv0 + n * 16 + lr;
#pragma unroll
          for (int r = 0; r < 4; ++r)
            sv[n][r] = (col <= qrow0 + r) ? sacc[n][r] : -1e30f;
        }
      }
      // ---- row max + defer-max (THR=8 in exp2 domain) ----
      float vmx[4];
#pragma unroll
      for (int r = 0; r < 4; ++r) {
        float v = fmaxf(fmaxf(sv[0][r], sv[1][r]), fmaxf(sv[2][r], sv[3][r]));
#pragma unroll
        for (int off = 1; off < 16; off <<= 1)
          v = fmaxf(v, __shfl_xor(v, off, 16));
        vmx[r] = v;
      }
      bool ok = true;
#pragma unroll
      for (int r = 0; r < 4; ++r) ok &= (vmx[r] <= m[r] + 8.f);
      if (!__all(ok)) {
        float al[4];
#pragma unroll
        for (int r = 0; r < 4; ++r) {
          float mn = fmaxf(m[r], vmx[r]);
          al[r] = fexp2(m[r] - mn);
          m[r] = mn;
          lsum[r] *= al[r];
        }
#pragma unroll
        for (int db = 0; db < 8; ++db)
#pragma unroll
          for (int r = 0; r < 4; ++r)
            oacc[db][r] *= al[r];
      }
      // ---- P = 2^(sv-m), write to LDS, row-sum ----
#pragma unroll
      for (int r = 0; r < 4; ++r) {
        const int prow = lg * 4 + r;
        const int pswz = (prow & 7) << 3;
        float ps = 0.f;
#pragma unroll
        for (int n = 0; n < 4; ++n) {
          float p = fexp2(sv[n][r] - m[r]);
          plds[w][prow * 64 + ((n * 16 + lr) ^ pswz)] = f2bf(p);
          ps += p;
        }
#pragma unroll
        for (int off = 1; off < 16; off <<= 1)
          ps += __shfl_xor(ps, off, 16);
        lsum[r] += ps;
      }
      // ---- PV (skip fully-masked 32-col halves) ----
      __builtin_amdgcn_s_setprio(1);
#pragma unroll
      for (int ks = 0; ks < 2; ++ks) {
        if (kv0 + ks * 32 > qmaxw) continue;   // wave-uniform, P==0 there
        const bf16x8 pf = *(const bf16x8*)&plds[w][lr * 64 + ((ks * 32 + lg * 8) ^ ((lr & 7) << 3))];
#pragma unroll
        for (int db = 0; db < 8; ++db) {
          const int vrow = db * 16 + lr;
          const bf16x8 vf = *(const bf16x8*)&vbuf[cur][vrow * 64 + ((ks * 32 + lg * 8) ^ ((vrow & 7) << 3))];
          oacc[db] = MFMA16(pf, vf, oacc[db]);
        }
      }
      __builtin_amdgcn_s_setprio(0);
    }
  }
#undef ASTAGE

  u16* Op = O + ((size_t)b * S_LEN + (size_t)qb * 128 + (size_t)w * 16) * HIDN + h * HD;
#pragma unroll
  for (int db = 0; db < 8; ++db)
#pragma unroll
    for (int r = 0; r < 4; ++r)
      Op[(size_t)(lg * 4 + r) * HIDN + db * 16 + lr] = f2bf(oacc[db][r] / lsum[r]);
}

// ---------------- launcher ----------------
extern "C" void kernel_launch(void* const* d_in, const int* in_sizes, int n_in,
                              void* d_out, int out_size, void* d_ws, size_t ws_size,
                              hipStream_t stream) {
  const int*   positions = (const int*)d_in[0];
  const float* hidden    = (const float*)d_in[1];
  const float* Wqkv      = (const float*)d_in[2];
  const float* bqkv      = (const float*)d_in[3];
  const float* Wo        = (const float*)d_in[4];
  const float* bo        = (const float*)d_in[5];
  float* out = (float*)d_out;
  char* ws = (char*)d_ws;

  // workspace layout (bytes)
  u16*   WqkvT = (u16*)(ws + 0);            // [12288][4096] bf16, 96 MiB
  u16*   WoT   = (u16*)(ws + 100663296);    // [4096][4096] bf16, 32 MiB
  u16*   Xb    = (u16*)(ws + 134217728);    // [4096][4096] bf16, 32 MiB
  float* cosT  = (float*)(ws + 167772160);  // [2048][64] f32
  float* sinT  = (float*)(ws + 168296448);
  // Q/K/Vt written directly by GEMM1's fused epilogue
  u16* Qr  = (u16*)(ws + 168820736);        // 32 MiB
  u16* Kr  = Qr + 16777216;                 // 32 MiB
  u16* Vtr = Kr + 16777216;                 // 32 MiB
  u16* Ob  = Xb;                            // Xb dead after GEMM1

  transpose_cast<<<dim3(384, 128), dim3(32, 8), 0, stream>>>(Wqkv, WqkvT, 4096, 12288);
  transpose_cast<<<dim3(128, 128), dim3(32, 8), 0, stream>>>(Wo, WoT, 4096, 4096);
  cast_bf16_k<<<16384, 256, 0, stream>>>(hidden, Xb, 4194304);
  rope_table_k<<<512, 256, 0, stream>>>(positions, cosT, sinT);
  gemm256<1><<<768, 512, 0, stream>>>(Xb, WqkvT, bqkv, nullptr, 4096, 12288, 4096, 16,
                                      Qr, Kr, Vtr, cosT, sinT);
  attn_k<<<1024, 512, 0, stream>>>(Qr, Kr, Vtr, Ob);
  gemm256<0><<<256, 512, 0, stream>>>(Ob, WoT, bo, out, 4096, 4096, 4096, 16,
                                      nullptr, nullptr, nullptr, nullptr, nullptr);
}

// Round 15
// 735.163 us; speedup vs baseline: 3.9630x; 3.9630x over previous
//
#include <hip/hip_runtime.h>
#include <hip/hip_bf16.h>

#define S_LEN 2048
#define HIDN  4096
#define NH    32
#define HD    128

typedef __attribute__((ext_vector_type(8))) __bf16 bf16x8;
typedef __attribute__((ext_vector_type(4))) float  f32x4;
typedef unsigned short u16;

__device__ __forceinline__ float bf2f(u16 u) {
  unsigned v = ((unsigned)u) << 16;
  return __builtin_bit_cast(float, v);
}
__device__ __forceinline__ u16 f2bf(float f) {
  unsigned u = __builtin_bit_cast(unsigned, f);
  u += 0x7FFFu + ((u >> 16) & 1u);
  return (u16)(u >> 16);
}
__device__ __forceinline__ float fexp2(float x) {   // 2^x, single v_exp_f32
  float r; asm("v_exp_f32 %0, %1" : "=v"(r) : "v"(x)); return r;
}
__device__ __forceinline__ void gload16(const void* g, void* l) {
  __builtin_amdgcn_global_load_lds((const __attribute__((address_space(1))) void*)g,
                                   (__attribute__((address_space(3))) void*)l, 16, 0, 0);
}
#define MFMA16(a, b, c) __builtin_amdgcn_mfma_f32_16x16x32_bf16(a, b, c, 0, 0, 0)

// ---------------- prep kernels ----------------

// f32 [R][C] -> bf16 [C][R]
__global__ void transpose_cast(const float* __restrict__ in, u16* __restrict__ out,
                               int R, int C) {
  __shared__ float t[32][33];
  const int c0 = blockIdx.x * 32, r0 = blockIdx.y * 32;
  const int tx = threadIdx.x, ty = threadIdx.y;
#pragma unroll
  for (int i = 0; i < 4; ++i)
    t[ty + i * 8][tx] = in[(size_t)(r0 + ty + i * 8) * C + c0 + tx];
  __syncthreads();
#pragma unroll
  for (int i = 0; i < 4; ++i)
    out[(size_t)(c0 + ty + i * 8) * R + r0 + tx] = f2bf(t[tx][ty + i * 8]);
}

struct u16x4s { u16 x, y, z, w; };

__global__ void cast_bf16_k(const float* __restrict__ in, u16* __restrict__ out, int n4) {
  int i = blockIdx.x * 256 + threadIdx.x;
  if (i < n4) {
    float4 v = ((const float4*)in)[i];
    u16x4s o;
    o.x = f2bf(v.x); o.y = f2bf(v.y); o.z = f2bf(v.z); o.w = f2bf(v.w);
    ((u16x4s*)out)[i] = o;
  }
}

__global__ void rope_table_k(const int* __restrict__ pos, float* __restrict__ cs,
                             float* __restrict__ sn) {
  int idx = blockIdx.x * 256 + threadIdx.x;   // S_LEN*64 total
  int s = idx >> 6, d = idx & 63;
  float inv = exp2f((-(float)d / 64.f) * 13.287712379549449f); // log2(10000)
  float ang = (float)pos[s] * inv;
  cs[idx] = cosf(ang);
  sn[idx] = sinf(ang);
}

// ---------------- 256x256 4-phase GEMM (16x16x32, R10-proven K-loop) ----------------
// EPI=0: plain f32 output (O-projection).
// EPI=1: fused QKV epilogue via LDS tile. Tile is slot-swizzled:
//   logical (row,col) -> lds[row*256 + (((col>>3) ^ (row&7))<<3) + (col&7)]
template <int EPI>
__global__ __launch_bounds__(512) void gemm256(
    const u16* __restrict__ A, const u16* __restrict__ Bt,
    const float* __restrict__ bias, void* __restrict__ Cv,
    int M, int N, int K, int nbm,
    u16* __restrict__ Qo, u16* __restrict__ Ko, u16* __restrict__ Vo,
    const float* __restrict__ cs, const float* __restrict__ sn) {
  __shared__ alignas(16) u16 lds[2][2][2][128 * 64];
  const int tid = threadIdx.x;
  const int cpx = gridDim.x >> 3;
  const int swz = (blockIdx.x & 7) * cpx + (blockIdx.x >> 3);   // bijective (nb%8==0)
  const int bm = (swz % nbm) * 256, bn = (swz / nbm) * 256;     // bm fastest: B reuse in L2
  const int w = tid >> 6, l = tid & 63;
  const int wm = w >> 2, wn = w & 3;
  const int lr = l & 15, lg = l >> 4;
  const int rswz = (lr & 7) * 8;                  // read-side XOR (u16 units)
  const int rl = tid >> 3;                        // staging row (per 8 threads)
  const int sl = (tid & 7) ^ ((tid >> 3) & 7);    // staging source slot (inverse swz)
  const u16* Ap = A + (size_t)bm * K;
  const u16* Bp = Bt + (size_t)bn * K;

#define STG(buf, ab, half, kt) do { \
    const u16* s_ = (ab ? Bp : Ap) + (size_t)((half) * 128 + rl) * K + (kt) * 64 + sl * 8; \
    u16* d_ = &lds[buf][ab][half][tid * 8]; \
    gload16(s_, d_); \
    gload16(s_ + (size_t)64 * K, d_ + 4096); \
  } while (0)

  f32x4 acc[8][4] = {};
  // prologue: K-tile 0 complete + K-tile 1 A halves = 12 loads
  STG(0, 0, 0, 0); STG(0, 0, 1, 0); STG(0, 1, 0, 0); STG(0, 1, 1, 0);
  STG(1, 0, 0, 1); STG(1, 0, 1, 1);
  asm volatile("s_waitcnt vmcnt(4)" ::: "memory");   // K-tile 0 landed
  __builtin_amdgcn_s_barrier();

  const int NT = K >> 6;
  bf16x8 alo[4][2], ahi[4][2], bfr[2][2];
  for (int t = 0; t < NT; ++t) {
    const int buf = t & 1;
    const u16* Al = &lds[buf][0][wm][0];
    const u16* Bl = &lds[buf][1][wn >> 1][0];
    const int brow = (wn & 1) * 64;
    // ---------- phase 1 ----------
#pragma unroll
    for (int mi = 0; mi < 4; ++mi)
#pragma unroll
      for (int ks = 0; ks < 2; ++ks)
        alo[mi][ks] = *(const bf16x8*)&Al[(mi * 16 + lr) * 64 + ((ks * 32 + lg * 8) ^ rswz)];
#pragma unroll
    for (int ni = 0; ni < 2; ++ni)
#pragma unroll
      for (int ks = 0; ks < 2; ++ks)
        bfr[ni][ks] = *(const bf16x8*)&Bl[(brow + ni * 16 + lr) * 64 + ((ks * 32 + lg * 8) ^ rswz)];
    if (t + 1 < NT) STG(buf ^ 1, 1, 0, t + 1);
    __builtin_amdgcn_s_barrier();
    __builtin_amdgcn_s_setprio(1);
#pragma unroll
    for (int mi = 0; mi < 4; ++mi)
#pragma unroll
      for (int ni = 0; ni < 2; ++ni)
#pragma unroll
        for (int ks = 0; ks < 2; ++ks)
          acc[mi][ni] = MFMA16(alo[mi][ks], bfr[ni][ks], acc[mi][ni]);
    __builtin_amdgcn_s_setprio(0);
    __builtin_amdgcn_s_barrier();
    // ---------- phase 2 ----------
#pragma unroll
    for (int mi = 0; mi < 4; ++mi)
#pragma unroll
      for (int ks = 0; ks < 2; ++ks)
        ahi[mi][ks] = *(const bf16x8*)&Al[((mi + 4) * 16 + lr) * 64 + ((ks * 32 + lg * 8) ^ rswz)];
    if (t + 1 < NT) STG(buf ^ 1, 1, 1, t + 1);
    __builtin_amdgcn_s_barrier();
    __builtin_amdgcn_s_setprio(1);
#pragma unroll
    for (int mi = 0; mi < 4; ++mi)
#pragma unroll
      for (int ni = 0; ni < 2; ++ni)
#pragma unroll
        for (int ks = 0; ks < 2; ++ks)
          acc[mi + 4][ni] = MFMA16(ahi[mi][ks], bfr[ni][ks], acc[mi + 4][ni]);
    __builtin_amdgcn_s_setprio(0);
    __builtin_amdgcn_s_barrier();
    // ---------- phase 3 ----------
#pragma unroll
    for (int ni = 0; ni < 2; ++ni)
#pragma unroll
      for (int ks = 0; ks < 2; ++ks)
        bfr[ni][ks] = *(const bf16x8*)&Bl[(brow + (ni + 2) * 16 + lr) * 64 + ((ks * 32 + lg * 8) ^ rswz)];
    if (t + 2 < NT) STG(buf, 0, 0, t + 2);
    __builtin_amdgcn_s_barrier();
    __builtin_amdgcn_s_setprio(1);
#pragma unroll
    for (int mi = 0; mi < 4; ++mi)
#pragma unroll
      for (int ni = 0; ni < 2; ++ni)
#pragma unroll
        for (int ks = 0; ks < 2; ++ks)
          acc[mi][ni + 2] = MFMA16(alo[mi][ks], bfr[ni][ks], acc[mi][ni + 2]);
    __builtin_amdgcn_s_setprio(0);
    __builtin_amdgcn_s_barrier();
    // ---------- phase 4 ----------
    if (t + 2 < NT) {
      STG(buf, 0, 1, t + 2);
      asm volatile("s_waitcnt vmcnt(4)" ::: "memory");  // all of K-tile t+1 landed
    } else {
      asm volatile("s_waitcnt vmcnt(0)" ::: "memory");
    }
    __builtin_amdgcn_s_barrier();
    __builtin_amdgcn_s_setprio(1);
#pragma unroll
    for (int mi = 0; mi < 4; ++mi)
#pragma unroll
      for (int ni = 0; ni < 2; ++ni)
#pragma unroll
        for (int ks = 0; ks < 2; ++ks)
          acc[mi + 4][ni + 2] = MFMA16(ahi[mi][ks], bfr[ni][ks], acc[mi + 4][ni + 2]);
    __builtin_amdgcn_s_setprio(0);
    __builtin_amdgcn_s_barrier();
  }
#undef STG

  if (EPI == 0) {
#pragma unroll
    for (int ni = 0; ni < 4; ++ni) {
      const int col = bn + wn * 64 + ni * 16 + lr;
      const float bv = bias[col];
#pragma unroll
      for (int mi = 0; mi < 8; ++mi) {
        const int row = bm + wm * 128 + mi * 16 + lg * 4;
#pragma unroll
        for (int r = 0; r < 4; ++r)
          ((float*)Cv)[(size_t)(row + r) * N + col] = acc[mi][ni][r] + bv;
      }
    }
  } else {
    // ---- fused QKV epilogue (slot-swizzled tile) ----
    u16* tile = (u16*)lds;          // 256x256 bf16 = 128 KiB (K-loop buffers dead)
    const int cr = lg * 4, cc = lr;
#pragma unroll
    for (int ni = 0; ni < 4; ++ni) {
      const int lcol = wn * 64 + ni * 16 + cc;
      const float bv = bias[bn + lcol];
#pragma unroll
      for (int mi = 0; mi < 8; ++mi) {
        const int lrow = wm * 128 + mi * 16 + cr;
#pragma unroll
        for (int r = 0; r < 4; ++r) {
          const int rw = lrow + r;
          tile[rw * 256 + ((((lcol >> 3) ^ (rw & 7)) << 3) | (lcol & 7))] =
              f2bf(acc[mi][ni][r] + bv);
        }
      }
    }
    __syncthreads();
    if (bn < 2 * HIDN) {
      // Q or K tile: rope pairs (d, d+64) same-thread via LDS
      const float sc = (bn < HIDN) ? 0.12751743f : 1.0f;  // (1/sqrt(128))*log2e in Q
      u16* dst0 = (bn < HIDN) ? Qo : Ko;
      const int hbase = (bn & (HIDN - 1)) >> 7;
#pragma unroll
      for (int it = 0; it < 8; ++it) {
        const int idx = it * 512 + tid;                   // 2 heads*256 s*8 chunks
        const int hh = idx >> 11, slc = (idx >> 3) & 255, d0 = (idx & 7) * 8;
        const int colA = hh * 128 + d0, colB = colA + 64;
        const bf16x8 va = *(const bf16x8*)&tile[slc * 256 + (((colA >> 3) ^ (slc & 7)) << 3)];
        const bf16x8 vb = *(const bf16x8*)&tile[slc * 256 + (((colB >> 3) ^ (slc & 7)) << 3)];
        const int sg = bm + slc, b_ = sg >> 11, s_ = sg & 2047;
        const float4 c0 = *(const float4*)&cs[s_ * 64 + d0];
        const float4 c1 = *(const float4*)&cs[s_ * 64 + d0 + 4];
        const float4 s0v = *(const float4*)&sn[s_ * 64 + d0];
        const float4 s1v = *(const float4*)&sn[s_ * 64 + d0 + 4];
        bf16x8 r1, r2;
#pragma unroll
        for (int j = 0; j < 8; ++j) {
          float x1 = (float)va[j], x2 = (float)vb[j];
          float cj = (j < 4) ? c0[j & 3] : c1[j & 3];
          float sj = (j < 4) ? s0v[j & 3] : s1v[j & 3];
          r1[j] = (__bf16)((x1 * cj - x2 * sj) * sc);
          r2[j] = (__bf16)((x2 * cj + x1 * sj) * sc);
        }
        u16* dp = dst0 + ((size_t)(b_ * NH + hbase + hh) * S_LEN + s_) * HD + d0;
        *(bf16x8*)dp = r1;
        *(bf16x8*)(dp + 64) = r2;
      }
    } else {
      // V tile: transpose to Vt[B,H,D,S]
      const int hbase = (bn - 2 * HIDN) >> 7;
#pragma unroll
      for (int it = 0; it < 16; ++it) {
        const int idx = it * 512 + tid;                   // 32 s-chunks * 256 cols
        const int sc8 = idx >> 8, cl = idx & 255;
        const int s0 = sc8 * 8;
        bf16x8 v;
#pragma unroll
        for (int j = 0; j < 8; ++j) {
          const int rw = s0 + j;
          v[j] = __builtin_bit_cast(__bf16,
                 tile[rw * 256 + ((((cl >> 3) ^ (rw & 7)) << 3) | (cl & 7))]);
        }
        const int sg = bm + s0, b_ = sg >> 11, s_ = sg & 2047;
        const int h_ = hbase + (cl >> 7), d_ = cl & 127;
        *(bf16x8*)&Vo[((size_t)(b_ * NH + h_) * HD + d_) * S_LEN + s_] = v;
      }
    }
  }
}

// ---------------- causal flash attention: 8 waves/block, QBLK=128 (R13) ----------
__global__ __launch_bounds__(512) void attn_k(
    const u16* __restrict__ Q, const u16* __restrict__ K,
    const u16* __restrict__ Vt, u16* __restrict__ O) {
  __shared__ alignas(16) u16 kbuf[2][64 * 128];
  __shared__ alignas(16) u16 vbuf[2][128 * 64];
  __shared__ alignas(16) u16 plds[8][16 * 64];
  const int blk = blockIdx.x;
  const int qb = 15 - (blk >> 6);          // longest blocks dispatch first
  const int bhid = blk & 63;
  const int b = bhid >> 5, h = bhid & 31;
  const int tid = threadIdx.x;
  const int w = tid >> 6, l = tid & 63;
  const int lr = l & 15, lg = l >> 4;
  const size_t bh = (size_t)(b * NH + h);
  const u16* Qp = Q + (bh * S_LEN + (size_t)qb * 128 + (size_t)w * 16) * HD;
  const u16* Kp = K + bh * S_LEN * HD;
  const u16* Vp = Vt + bh * HD * S_LEN;

  bf16x8 qf[4];
#pragma unroll
  for (int kd = 0; kd < 4; ++kd)
    qf[kd] = *(const bf16x8*)&Qp[lr * HD + kd * 32 + lg * 8];

  f32x4 oacc[8] = {};
  float m[4], lsum[4];
#pragma unroll
  for (int r = 0; r < 4; ++r) { m[r] = -1e30f; lsum[r] = 0.f; }
  const int nsteps = 2 * qb + 2;
  const int qmin = qb * 128 + w * 16;      // wave-uniform first q row
  const int qmaxw = qmin + 15;
  const int qrow0 = qmin + lg * 4;

#define ASTAGE(buf, kv0) do { \
    _Pragma("unroll") \
    for (int c = 0; c < 2; ++c) { \
      const int kr = c * 32 + (tid >> 4); \
      const int kc = ((tid & 15) * 8) ^ ((kr & 7) << 3); \
      gload16(Kp + (size_t)((kv0) + kr) * HD + kc, &kbuf[buf][c * 4096 + tid * 8]); \
      const int vr = c * 64 + (tid >> 3); \
      const int vc = ((tid & 7) * 8) ^ ((vr & 7) << 3); \
      gload16(Vp + (size_t)vr * S_LEN + (kv0) + vc, &vbuf[buf][c * 4096 + tid * 8]); \
    } \
  } while (0)

  ASTAGE(0, 0);
  for (int st = 0; st < nsteps; ++st) {
    const int kv0 = st * 64;
    const int cur = st & 1;
    __syncthreads();                       // stage(cur) landed; buf cur^1 free
    if (st + 1 < nsteps) ASTAGE(cur ^ 1, kv0 + 64);

    if (kv0 <= qmaxw) {                    // wave-uniform: skip fully-masked steps
      const int na0 = ((qmaxw - kv0) >> 4) + 1;
      const int na = na0 > 4 ? 4 : na0;    // active 16-col n-blocks (wave-uniform)

      // ---- QK^T (active n-blocks only) ----
      f32x4 sacc[4] = {};
      __builtin_amdgcn_s_setprio(1);
#pragma unroll
      for (int n = 0; n < 4; ++n) {
        if (n < na) {
          const int krow = n * 16 + lr;
          const int swzk = (krow & 7) << 3;
#pragma unroll
          for (int kd = 0; kd < 4; ++kd) {
            const bf16x8 kf = *(const bf16x8*)&kbuf[cur][krow * 128 + ((kd * 32 + lg * 8) ^ swzk)];
            sacc[n] = MFMA16(qf[kd], kf, sacc[n]);
          }
        }
      }
      __builtin_amdgcn_s_setprio(0);
      // ---- causal mask (skip when step fully below diagonal) ----
      float sv[4][4];
      if (kv0 + 63 <= qmin) {
#pragma unroll
        for (int n = 0; n < 4; ++n)
#pragma unroll
          for (int r = 0; r < 4; ++r) sv[n][r] = sacc[n][r];
      } else {
#pragma unroll
        for (int n = 0; n < 4; ++n) {
          const int col = kv0 + n * 16 + lr;
#pragma unroll
          for (int r = 0; r < 4; ++r)
            sv[n][r] = (col <= qrow0 + r) ? sacc[n][r] : -1e30f;
        }
      }
      // ---- row max + defer-max (THR=8 in exp2 domain) ----
      float vmx[4];
#pragma unroll
      for (int r = 0; r < 4; ++r) {
        float v = fmaxf(fmaxf(sv[0][r], sv[1][r]), fmaxf(sv[2][r], sv[3][r]));
#pragma unroll
        for (int off = 1; off < 16; off <<= 1)
          v = fmaxf(v, __shfl_xor(v, off, 16));
        vmx[r] = v;
      }
      bool ok = true;
#pragma unroll
      for (int r = 0; r < 4; ++r) ok &= (vmx[r] <= m[r] + 8.f);
      if (!__all(ok)) {
        float al[4];
#pragma unroll
        for (int r = 0; r < 4; ++r) {
          float mn = fmaxf(m[r], vmx[r]);
          al[r] = fexp2(m[r] - mn);
          m[r] = mn;
          lsum[r] *= al[r];
        }
#pragma unroll
        for (int db = 0; db < 8; ++db)
#pragma unroll
          for (int r = 0; r < 4; ++r)
            oacc[db][r] *= al[r];
      }
      // ---- P = 2^(sv-m), write to LDS, row-sum ----
#pragma unroll
      for (int r = 0; r < 4; ++r) {
        const int prow = lg * 4 + r;
        const int pswz = (prow & 7) << 3;
        float ps = 0.f;
#pragma unroll
        for (int n = 0; n < 4; ++n) {
          float p = fexp2(sv[n][r] - m[r]);
          plds[w][prow * 64 + ((n * 16 + lr) ^ pswz)] = f2bf(p);
          ps += p;
        }
#pragma unroll
        for (int off = 1; off < 16; off <<= 1)
          ps += __shfl_xor(ps, off, 16);
        lsum[r] += ps;
      }
      // ---- PV (skip fully-masked 32-col halves) ----
      __builtin_amdgcn_s_setprio(1);
#pragma unroll
      for (int ks = 0; ks < 2; ++ks) {
        if (kv0 + ks * 32 > qmaxw) continue;   // wave-uniform, P==0 there
        const bf16x8 pf = *(const bf16x8*)&plds[w][lr * 64 + ((ks * 32 + lg * 8) ^ ((lr & 7) << 3))];
#pragma unroll
        for (int db = 0; db < 8; ++db) {
          const int vrow = db * 16 + lr;
          const bf16x8 vf = *(const bf16x8*)&vbuf[cur][vrow * 64 + ((ks * 32 + lg * 8) ^ ((vrow & 7) << 3))];
          oacc[db] = MFMA16(pf, vf, oacc[db]);
        }
      }
      __builtin_amdgcn_s_setprio(0);
    }
  }
#undef ASTAGE

  u16* Op = O + ((size_t)b * S_LEN + (size_t)qb * 128 + (size_t)w * 16) * HIDN + h * HD;
#pragma unroll
  for (int db = 0; db < 8; ++db)
#pragma unroll
    for (int r = 0; r < 4; ++r)
      Op[(size_t)(lg * 4 + r) * HIDN + db * 16 + lr] = f2bf(oacc[db][r] / lsum[r]);
}

// ---------------- launcher ----------------
extern "C" void kernel_launch(void* const* d_in, const int* in_sizes, int n_in,
                              void* d_out, int out_size, void* d_ws, size_t ws_size,
                              hipStream_t stream) {
  const int*   positions = (const int*)d_in[0];
  const float* hidden    = (const float*)d_in[1];
  const float* Wqkv      = (const float*)d_in[2];
  const float* bqkv      = (const float*)d_in[3];
  const float* Wo        = (const float*)d_in[4];
  const float* bo        = (const float*)d_in[5];
  float* out = (float*)d_out;
  char* ws = (char*)d_ws;

  // workspace layout (bytes)
  u16*   WqkvT = (u16*)(ws + 0);            // [12288][4096] bf16, 96 MiB
  u16*   WoT   = (u16*)(ws + 100663296);    // [4096][4096] bf16, 32 MiB
  u16*   Xb    = (u16*)(ws + 134217728);    // [4096][4096] bf16, 32 MiB
  float* cosT  = (float*)(ws + 167772160);  // [2048][64] f32
  float* sinT  = (float*)(ws + 168296448);
  // Q/K/Vt written directly by GEMM1's fused epilogue
  u16* Qr  = (u16*)(ws + 168820736);        // 32 MiB
  u16* Kr  = Qr + 16777216;                 // 32 MiB
  u16* Vtr = Kr + 16777216;                 // 32 MiB
  u16* Ob  = Xb;                            // Xb dead after GEMM1

  transpose_cast<<<dim3(384, 128), dim3(32, 8), 0, stream>>>(Wqkv, WqkvT, 4096, 12288);
  transpose_cast<<<dim3(128, 128), dim3(32, 8), 0, stream>>>(Wo, WoT, 4096, 4096);
  cast_bf16_k<<<16384, 256, 0, stream>>>(hidden, Xb, 4194304);
  rope_table_k<<<512, 256, 0, stream>>>(positions, cosT, sinT);
  gemm256<1><<<768, 512, 0, stream>>>(Xb, WqkvT, bqkv, nullptr, 4096, 12288, 4096, 16,
                                      Qr, Kr, Vtr, cosT, sinT);
  attn_k<<<1024, 512, 0, stream>>>(Qr, Kr, Vtr, Ob);
  gemm256<0><<<256, 512, 0, stream>>>(Ob, WoT, bo, out, 4096, 4096, 4096, 16,
                                      nullptr, nullptr, nullptr, nullptr, nullptr);
}

// Round 16
// 726.860 us; speedup vs baseline: 4.0083x; 1.0114x over previous
//
#include <hip/hip_runtime.h>
#include <hip/hip_bf16.h>

#define S_LEN 2048
#define HIDN  4096
#define NH    32
#define HD    128

typedef __attribute__((ext_vector_type(8))) __bf16 bf16x8;
typedef __attribute__((ext_vector_type(4))) float  f32x4;
typedef unsigned short u16;

__device__ __forceinline__ float bf2f(u16 u) {
  unsigned v = ((unsigned)u) << 16;
  return __builtin_bit_cast(float, v);
}
__device__ __forceinline__ u16 f2bf(float f) {
  unsigned u = __builtin_bit_cast(unsigned, f);
  u += 0x7FFFu + ((u >> 16) & 1u);
  return (u16)(u >> 16);
}
__device__ __forceinline__ float fexp2(float x) {   // 2^x, single v_exp_f32
  float r; asm("v_exp_f32 %0, %1" : "=v"(r) : "v"(x)); return r;
}
__device__ __forceinline__ void gload16(const void* g, void* l) {
  __builtin_amdgcn_global_load_lds((const __attribute__((address_space(1))) void*)g,
                                   (__attribute__((address_space(3))) void*)l, 16, 0, 0);
}
#define MFMA16(a, b, c) __builtin_amdgcn_mfma_f32_16x16x32_bf16(a, b, c, 0, 0, 0)

// ---------------- prep kernels ----------------

// f32 [R][C] -> bf16 [C][R]
__global__ void transpose_cast(const float* __restrict__ in, u16* __restrict__ out,
                               int R, int C) {
  __shared__ float t[32][33];
  const int c0 = blockIdx.x * 32, r0 = blockIdx.y * 32;
  const int tx = threadIdx.x, ty = threadIdx.y;
#pragma unroll
  for (int i = 0; i < 4; ++i)
    t[ty + i * 8][tx] = in[(size_t)(r0 + ty + i * 8) * C + c0 + tx];
  __syncthreads();
#pragma unroll
  for (int i = 0; i < 4; ++i)
    out[(size_t)(c0 + ty + i * 8) * R + r0 + tx] = f2bf(t[tx][ty + i * 8]);
}

struct u16x4s { u16 x, y, z, w; };

__global__ void cast_bf16_k(const float* __restrict__ in, u16* __restrict__ out, int n4) {
  int i = blockIdx.x * 256 + threadIdx.x;
  if (i < n4) {
    float4 v = ((const float4*)in)[i];
    u16x4s o;
    o.x = f2bf(v.x); o.y = f2bf(v.y); o.z = f2bf(v.z); o.w = f2bf(v.w);
    ((u16x4s*)out)[i] = o;
  }
}

__global__ void rope_table_k(const int* __restrict__ pos, float* __restrict__ cs,
                             float* __restrict__ sn) {
  int idx = blockIdx.x * 256 + threadIdx.x;   // S_LEN*64 total
  int s = idx >> 6, d = idx & 63;
  float inv = exp2f((-(float)d / 64.f) * 13.287712379549449f); // log2(10000)
  float ang = (float)pos[s] * inv;
  cs[idx] = cosf(ang);
  sn[idx] = sinf(ang);
}

// ---------------- 256x256 4-phase GEMM (16x16x32, R5 schedule, x2-unrolled) --------
// EPI=0: plain f32 output (O-projection).
// EPI=1: fused QKV epilogue via slot-swizzled LDS tile (R13-proven).
// NEW vs R15: K-loop unrolled 2 tiles/iter with COMPILE-TIME buffer index ->
// all 24 ds_read addresses/wave/tile fold into per-buffer bases + offset:
// immediates (removes per-tile VALU address recompute). Sync structure,
// staging slots, vmcnt placement identical to the proven R5 schedule.
template <int EPI>
__global__ __launch_bounds__(512) void gemm256(
    const u16* __restrict__ A, const u16* __restrict__ Bt,
    const float* __restrict__ bias, void* __restrict__ Cv,
    int M, int N, int K, int nbm,
    u16* __restrict__ Qo, u16* __restrict__ Ko, u16* __restrict__ Vo,
    const float* __restrict__ cs, const float* __restrict__ sn) {
  __shared__ alignas(16) u16 lds[2][2][2][128 * 64];
  const int tid = threadIdx.x;
  const int cpx = gridDim.x >> 3;
  const int swz = (blockIdx.x & 7) * cpx + (blockIdx.x >> 3);   // bijective (nb%8==0)
  const int bm = (swz % nbm) * 256, bn = (swz / nbm) * 256;     // bm fastest: B reuse in L2
  const int w = tid >> 6, l = tid & 63;
  const int wm = w >> 2, wn = w & 3;
  const int lr = l & 15, lg = l >> 4;
  const int rswz = (lr & 7) * 8;                  // read-side XOR (u16 units)
  const int rl = tid >> 3;                        // staging row (per 8 threads)
  const int sl = (tid & 7) ^ ((tid >> 3) & 7);    // staging source slot (inverse swz)
  const u16* Ap = A + (size_t)bm * K;
  const u16* Bp = Bt + (size_t)bn * K;

#define STG(buf, ab, half, kt) do { \
    const u16* s_ = (ab ? Bp : Ap) + (size_t)((half) * 128 + rl) * K + (kt) * 64 + sl * 8; \
    u16* d_ = &lds[buf][ab][half][tid * 8]; \
    gload16(s_, d_); \
    gload16(s_ + (size_t)64 * K, d_ + 4096); \
  } while (0)

  f32x4 acc[8][4] = {};
  // prologue: K-tile 0 complete + K-tile 1 A halves = 12 loads
  STG(0, 0, 0, 0); STG(0, 0, 1, 0); STG(0, 1, 0, 0); STG(0, 1, 1, 0);
  STG(1, 0, 0, 1); STG(1, 0, 1, 1);
  asm volatile("s_waitcnt vmcnt(4)" ::: "memory");   // K-tile 0 landed
  __builtin_amdgcn_s_barrier();

  const int NT = K >> 6;
  bf16x8 alo[4][2], ahi[4][2], bfr[2][2];

  // One K-tile with compile-time BUF: phases/staging/vmcnt identical to R5.
#define KTILE(BUF, t) do { \
    const u16* Al = &lds[BUF][0][wm][0]; \
    const u16* Bl = &lds[BUF][1][wn >> 1][0]; \
    const int brow = (wn & 1) * 64; \
    /* ---------- phase 1 ---------- */ \
    _Pragma("unroll") for (int mi = 0; mi < 4; ++mi) \
      _Pragma("unroll") for (int ks = 0; ks < 2; ++ks) \
        alo[mi][ks] = *(const bf16x8*)&Al[(mi * 16 + lr) * 64 + ((ks * 32 + lg * 8) ^ rswz)]; \
    _Pragma("unroll") for (int ni = 0; ni < 2; ++ni) \
      _Pragma("unroll") for (int ks = 0; ks < 2; ++ks) \
        bfr[ni][ks] = *(const bf16x8*)&Bl[(brow + ni * 16 + lr) * 64 + ((ks * 32 + lg * 8) ^ rswz)]; \
    if ((t) + 1 < NT) STG(BUF ^ 1, 1, 0, (t) + 1); \
    __builtin_amdgcn_s_barrier(); \
    __builtin_amdgcn_s_setprio(1); \
    _Pragma("unroll") for (int mi = 0; mi < 4; ++mi) \
      _Pragma("unroll") for (int ni = 0; ni < 2; ++ni) \
        _Pragma("unroll") for (int ks = 0; ks < 2; ++ks) \
          acc[mi][ni] = MFMA16(alo[mi][ks], bfr[ni][ks], acc[mi][ni]); \
    __builtin_amdgcn_s_setprio(0); \
    __builtin_amdgcn_s_barrier(); \
    /* ---------- phase 2 ---------- */ \
    _Pragma("unroll") for (int mi = 0; mi < 4; ++mi) \
      _Pragma("unroll") for (int ks = 0; ks < 2; ++ks) \
        ahi[mi][ks] = *(const bf16x8*)&Al[((mi + 4) * 16 + lr) * 64 + ((ks * 32 + lg * 8) ^ rswz)]; \
    if ((t) + 1 < NT) STG(BUF ^ 1, 1, 1, (t) + 1); \
    __builtin_amdgcn_s_barrier(); \
    __builtin_amdgcn_s_setprio(1); \
    _Pragma("unroll") for (int mi = 0; mi < 4; ++mi) \
      _Pragma("unroll") for (int ni = 0; ni < 2; ++ni) \
        _Pragma("unroll") for (int ks = 0; ks < 2; ++ks) \
          acc[mi + 4][ni] = MFMA16(ahi[mi][ks], bfr[ni][ks], acc[mi + 4][ni]); \
    __builtin_amdgcn_s_setprio(0); \
    __builtin_amdgcn_s_barrier(); \
    /* ---------- phase 3 ---------- */ \
    _Pragma("unroll") for (int ni = 0; ni < 2; ++ni) \
      _Pragma("unroll") for (int ks = 0; ks < 2; ++ks) \
        bfr[ni][ks] = *(const bf16x8*)&Bl[(brow + (ni + 2) * 16 + lr) * 64 + ((ks * 32 + lg * 8) ^ rswz)]; \
    if ((t) + 2 < NT) STG(BUF, 0, 0, (t) + 2); \
    __builtin_amdgcn_s_barrier(); \
    __builtin_amdgcn_s_setprio(1); \
    _Pragma("unroll") for (int mi = 0; mi < 4; ++mi) \
      _Pragma("unroll") for (int ni = 0; ni < 2; ++ni) \
        _Pragma("unroll") for (int ks = 0; ks < 2; ++ks) \
          acc[mi][ni + 2] = MFMA16(alo[mi][ks], bfr[ni][ks], acc[mi][ni + 2]); \
    __builtin_amdgcn_s_setprio(0); \
    __builtin_amdgcn_s_barrier(); \
    /* ---------- phase 4 ---------- */ \
    if ((t) + 2 < NT) { \
      STG(BUF, 0, 1, (t) + 2); \
      asm volatile("s_waitcnt vmcnt(4)" ::: "memory");  /* tile t+1 landed */ \
    } else { \
      asm volatile("s_waitcnt vmcnt(0)" ::: "memory"); \
    } \
    __builtin_amdgcn_s_barrier(); \
    __builtin_amdgcn_s_setprio(1); \
    _Pragma("unroll") for (int mi = 0; mi < 4; ++mi) \
      _Pragma("unroll") for (int ni = 0; ni < 2; ++ni) \
        _Pragma("unroll") for (int ks = 0; ks < 2; ++ks) \
          acc[mi + 4][ni + 2] = MFMA16(ahi[mi][ks], bfr[ni][ks], acc[mi + 4][ni + 2]); \
    __builtin_amdgcn_s_setprio(0); \
    __builtin_amdgcn_s_barrier(); \
  } while (0)

  for (int t = 0; t < NT; t += 2) {   // NT even (K=4096 -> 64)
    KTILE(0, t);
    KTILE(1, t + 1);
  }
#undef KTILE
#undef STG

  if (EPI == 0) {
#pragma unroll
    for (int ni = 0; ni < 4; ++ni) {
      const int col = bn + wn * 64 + ni * 16 + lr;
      const float bv = bias[col];
#pragma unroll
      for (int mi = 0; mi < 8; ++mi) {
        const int row = bm + wm * 128 + mi * 16 + lg * 4;
#pragma unroll
        for (int r = 0; r < 4; ++r)
          ((float*)Cv)[(size_t)(row + r) * N + col] = acc[mi][ni][r] + bv;
      }
    }
  } else {
    // ---- fused QKV epilogue (slot-swizzled tile) ----
    u16* tile = (u16*)lds;          // 256x256 bf16 = 128 KiB (K-loop buffers dead)
    const int cr = lg * 4, cc = lr;
#pragma unroll
    for (int ni = 0; ni < 4; ++ni) {
      const int lcol = wn * 64 + ni * 16 + cc;
      const float bv = bias[bn + lcol];
#pragma unroll
      for (int mi = 0; mi < 8; ++mi) {
        const int lrow = wm * 128 + mi * 16 + cr;
#pragma unroll
        for (int r = 0; r < 4; ++r) {
          const int rw = lrow + r;
          tile[rw * 256 + ((((lcol >> 3) ^ (rw & 7)) << 3) | (lcol & 7))] =
              f2bf(acc[mi][ni][r] + bv);
        }
      }
    }
    __syncthreads();
    if (bn < 2 * HIDN) {
      // Q or K tile: rope pairs (d, d+64) same-thread via LDS
      const float sc = (bn < HIDN) ? 0.12751743f : 1.0f;  // (1/sqrt(128))*log2e in Q
      u16* dst0 = (bn < HIDN) ? Qo : Ko;
      const int hbase = (bn & (HIDN - 1)) >> 7;
#pragma unroll
      for (int it = 0; it < 8; ++it) {
        const int idx = it * 512 + tid;                   // 2 heads*256 s*8 chunks
        const int hh = idx >> 11, slc = (idx >> 3) & 255, d0 = (idx & 7) * 8;
        const int colA = hh * 128 + d0, colB = colA + 64;
        const bf16x8 va = *(const bf16x8*)&tile[slc * 256 + (((colA >> 3) ^ (slc & 7)) << 3)];
        const bf16x8 vb = *(const bf16x8*)&tile[slc * 256 + (((colB >> 3) ^ (slc & 7)) << 3)];
        const int sg = bm + slc, b_ = sg >> 11, s_ = sg & 2047;
        const float4 c0 = *(const float4*)&cs[s_ * 64 + d0];
        const float4 c1 = *(const float4*)&cs[s_ * 64 + d0 + 4];
        const float4 s0v = *(const float4*)&sn[s_ * 64 + d0];
        const float4 s1v = *(const float4*)&sn[s_ * 64 + d0 + 4];
        bf16x8 r1, r2;
#pragma unroll
        for (int j = 0; j < 8; ++j) {
          float x1 = (float)va[j], x2 = (float)vb[j];
          float cj = (j < 4) ? c0[j & 3] : c1[j & 3];
          float sj = (j < 4) ? s0v[j & 3] : s1v[j & 3];
          r1[j] = (__bf16)((x1 * cj - x2 * sj) * sc);
          r2[j] = (__bf16)((x2 * cj + x1 * sj) * sc);
        }
        u16* dp = dst0 + ((size_t)(b_ * NH + hbase + hh) * S_LEN + s_) * HD + d0;
        *(bf16x8*)dp = r1;
        *(bf16x8*)(dp + 64) = r2;
      }
    } else {
      // V tile: transpose to Vt[B,H,D,S]
      const int hbase = (bn - 2 * HIDN) >> 7;
#pragma unroll
      for (int it = 0; it < 16; ++it) {
        const int idx = it * 512 + tid;                   // 32 s-chunks * 256 cols
        const int sc8 = idx >> 8, cl = idx & 255;
        const int s0 = sc8 * 8;
        bf16x8 v;
#pragma unroll
        for (int j = 0; j < 8; ++j) {
          const int rw = s0 + j;
          v[j] = __builtin_bit_cast(__bf16,
                 tile[rw * 256 + ((((cl >> 3) ^ (rw & 7)) << 3) | (cl & 7))]);
        }
        const int sg = bm + s0, b_ = sg >> 11, s_ = sg & 2047;
        const int h_ = hbase + (cl >> 7), d_ = cl & 127;
        *(bf16x8*)&Vo[((size_t)(b_ * NH + h_) * HD + d_) * S_LEN + s_] = v;
      }
    }
  }
}

// ---------------- causal flash attention: 8 waves/block, QBLK=128 (R13) ----------
__global__ __launch_bounds__(512) void attn_k(
    const u16* __restrict__ Q, const u16* __restrict__ K,
    const u16* __restrict__ Vt, u16* __restrict__ O) {
  __shared__ alignas(16) u16 kbuf[2][64 * 128];
  __shared__ alignas(16) u16 vbuf[2][128 * 64];
  __shared__ alignas(16) u16 plds[8][16 * 64];
  const int blk = blockIdx.x;
  const int qb = 15 - (blk >> 6);          // longest blocks dispatch first
  const int bhid = blk & 63;
  const int b = bhid >> 5, h = bhid & 31;
  const int tid = threadIdx.x;
  const int w = tid >> 6, l = tid & 63;
  const int lr = l & 15, lg = l >> 4;
  const size_t bh = (size_t)(b * NH + h);
  const u16* Qp = Q + (bh * S_LEN + (size_t)qb * 128 + (size_t)w * 16) * HD;
  const u16* Kp = K + bh * S_LEN * HD;
  const u16* Vp = Vt + bh * HD * S_LEN;

  bf16x8 qf[4];
#pragma unroll
  for (int kd = 0; kd < 4; ++kd)
    qf[kd] = *(const bf16x8*)&Qp[lr * HD + kd * 32 + lg * 8];

  f32x4 oacc[8] = {};
  float m[4], lsum[4];
#pragma unroll
  for (int r = 0; r < 4; ++r) { m[r] = -1e30f; lsum[r] = 0.f; }
  const int nsteps = 2 * qb + 2;
  const int qmin = qb * 128 + w * 16;      // wave-uniform first q row
  const int qmaxw = qmin + 15;
  const int qrow0 = qmin + lg * 4;

#define ASTAGE(buf, kv0) do { \
    _Pragma("unroll") \
    for (int c = 0; c < 2; ++c) { \
      const int kr = c * 32 + (tid >> 4); \
      const int kc = ((tid & 15) * 8) ^ ((kr & 7) << 3); \
      gload16(Kp + (size_t)((kv0) + kr) * HD + kc, &kbuf[buf][c * 4096 + tid * 8]); \
      const int vr = c * 64 + (tid >> 3); \
      const int vc = ((tid & 7) * 8) ^ ((vr & 7) << 3); \
      gload16(Vp + (size_t)vr * S_LEN + (kv0) + vc, &vbuf[buf][c * 4096 + tid * 8]); \
    } \
  } while (0)

  ASTAGE(0, 0);
  for (int st = 0; st < nsteps; ++st) {
    const int kv0 = st * 64;
    const int cur = st & 1;
    __syncthreads();                       // stage(cur) landed; buf cur^1 free
    if (st + 1 < nsteps) ASTAGE(cur ^ 1, kv0 + 64);

    if (kv0 <= qmaxw) {                    // wave-uniform: skip fully-masked steps
      const int na0 = ((qmaxw - kv0) >> 4) + 1;
      const int na = na0 > 4 ? 4 : na0;    // active 16-col n-blocks (wave-uniform)

      // ---- QK^T (active n-blocks only) ----
      f32x4 sacc[4] = {};
      __builtin_amdgcn_s_setprio(1);
#pragma unroll
      for (int n = 0; n < 4; ++n) {
        if (n < na) {
          const int krow = n * 16 + lr;
          const int swzk = (krow & 7) << 3;
#pragma unroll
          for (int kd = 0; kd < 4; ++kd) {
            const bf16x8 kf = *(const bf16x8*)&kbuf[cur][krow * 128 + ((kd * 32 + lg * 8) ^ swzk)];
            sacc[n] = MFMA16(qf[kd], kf, sacc[n]);
          }
        }
      }
      __builtin_amdgcn_s_setprio(0);
      // ---- causal mask (skip when step fully below diagonal) ----
      float sv[4][4];
      if (kv0 + 63 <= qmin) {
#pragma unroll
        for (int n = 0; n < 4; ++n)
#pragma unroll
          for (int r = 0; r < 4; ++r) sv[n][r] = sacc[n][r];
      } else {
#pragma unroll
        for (int n = 0; n < 4; ++n) {
          const int col = kv0 + n * 16 + lr;
#pragma unroll
          for (int r = 0; r < 4; ++r)
            sv[n][r] = (col <= qrow0 + r) ? sacc[n][r] : -1e30f;
        }
      }
      // ---- row max + defer-max (THR=8 in exp2 domain) ----
      float vmx[4];
#pragma unroll
      for (int r = 0; r < 4; ++r) {
        float v = fmaxf(fmaxf(sv[0][r], sv[1][r]), fmaxf(sv[2][r], sv[3][r]));
#pragma unroll
        for (int off = 1; off < 16; off <<= 1)
          v = fmaxf(v, __shfl_xor(v, off, 16));
        vmx[r] = v;
      }
      bool ok = true;
#pragma unroll
      for (int r = 0; r < 4; ++r) ok &= (vmx[r] <= m[r] + 8.f);
      if (!__all(ok)) {
        float al[4];
#pragma unroll
        for (int r = 0; r < 4; ++r) {
          float mn = fmaxf(m[r], vmx[r]);
          al[r] = fexp2(m[r] - mn);
          m[r] = mn;
          lsum[r] *= al[r];
        }
#pragma unroll
        for (int db = 0; db < 8; ++db)
#pragma unroll
          for (int r = 0; r < 4; ++r)
            oacc[db][r] *= al[r];
      }
      // ---- P = 2^(sv-m), write to LDS, row-sum ----
#pragma unroll
      for (int r = 0; r < 4; ++r) {
        const int prow = lg * 4 + r;
        const int pswz = (prow & 7) << 3;
        float ps = 0.f;
#pragma unroll
        for (int n = 0; n < 4; ++n) {
          float p = fexp2(sv[n][r] - m[r]);
          plds[w][prow * 64 + ((n * 16 + lr) ^ pswz)] = f2bf(p);
          ps += p;
        }
#pragma unroll
        for (int off = 1; off < 16; off <<= 1)
          ps += __shfl_xor(ps, off, 16);
        lsum[r] += ps;
      }
      // ---- PV (skip fully-masked 32-col halves) ----
      __builtin_amdgcn_s_setprio(1);
#pragma unroll
      for (int ks = 0; ks < 2; ++ks) {
        if (kv0 + ks * 32 > qmaxw) continue;   // wave-uniform, P==0 there
        const bf16x8 pf = *(const bf16x8*)&plds[w][lr * 64 + ((ks * 32 + lg * 8) ^ ((lr & 7) << 3))];
#pragma unroll
        for (int db = 0; db < 8; ++db) {
          const int vrow = db * 16 + lr;
          const bf16x8 vf = *(const bf16x8*)&vbuf[cur][vrow * 64 + ((ks * 32 + lg * 8) ^ ((vrow & 7) << 3))];
          oacc[db] = MFMA16(pf, vf, oacc[db]);
        }
      }
      __builtin_amdgcn_s_setprio(0);
    }
  }
#undef ASTAGE

  u16* Op = O + ((size_t)b * S_LEN + (size_t)qb * 128 + (size_t)w * 16) * HIDN + h * HD;
#pragma unroll
  for (int db = 0; db < 8; ++db)
#pragma unroll
    for (int r = 0; r < 4; ++r)
      Op[(size_t)(lg * 4 + r) * HIDN + db * 16 + lr] = f2bf(oacc[db][r] / lsum[r]);
}

// ---------------- launcher ----------------
extern "C" void kernel_launch(void* const* d_in, const int* in_sizes, int n_in,
                              void* d_out, int out_size, void* d_ws, size_t ws_size,
                              hipStream_t stream) {
  const int*   positions = (const int*)d_in[0];
  const float* hidden    = (const float*)d_in[1];
  const float* Wqkv      = (const float*)d_in[2];
  const float* bqkv      = (const float*)d_in[3];
  const float* Wo        = (const float*)d_in[4];
  const float* bo        = (const float*)d_in[5];
  float* out = (float*)d_out;
  char* ws = (char*)d_ws;

  // workspace layout (bytes)
  u16*   WqkvT = (u16*)(ws + 0);            // [12288][4096] bf16, 96 MiB
  u16*   WoT   = (u16*)(ws + 100663296);    // [4096][4096] bf16, 32 MiB
  u16*   Xb    = (u16*)(ws + 134217728);    // [4096][4096] bf16, 32 MiB
  float* cosT  = (float*)(ws + 167772160);  // [2048][64] f32
  float* sinT  = (float*)(ws + 168296448);
  // Q/K/Vt written directly by GEMM1's fused epilogue
  u16* Qr  = (u16*)(ws + 168820736);        // 32 MiB
  u16* Kr  = Qr + 16777216;                 // 32 MiB
  u16* Vtr = Kr + 16777216;                 // 32 MiB
  u16* Ob  = Xb;                            // Xb dead after GEMM1

  transpose_cast<<<dim3(384, 128), dim3(32, 8), 0, stream>>>(Wqkv, WqkvT, 4096, 12288);
  transpose_cast<<<dim3(128, 128), dim3(32, 8), 0, stream>>>(Wo, WoT, 4096, 4096);
  cast_bf16_k<<<16384, 256, 0, stream>>>(hidden, Xb, 4194304);
  rope_table_k<<<512, 256, 0, stream>>>(positions, cosT, sinT);
  gemm256<1><<<768, 512, 0, stream>>>(Xb, WqkvT, bqkv, nullptr, 4096, 12288, 4096, 16,
                                      Qr, Kr, Vtr, cosT, sinT);
  attn_k<<<1024, 512, 0, stream>>>(Qr, Kr, Vtr, Ob);
  gemm256<0><<<256, 512, 0, stream>>>(Ob, WoT, bo, out, 4096, 4096, 4096, 16,
                                      nullptr, nullptr, nullptr, nullptr, nullptr);
}

// Round 17
// 724.771 us; speedup vs baseline: 4.0198x; 1.0029x over previous
//
#include <hip/hip_runtime.h>
#include <hip/hip_bf16.h>

#define S_LEN 2048
#define HIDN  4096
#define NH    32
#define HD    128

typedef __attribute__((ext_vector_type(8))) __bf16 bf16x8;
typedef __attribute__((ext_vector_type(4))) float  f32x4;
typedef unsigned short u16;

__device__ __forceinline__ float bf2f(u16 u) {
  unsigned v = ((unsigned)u) << 16;
  return __builtin_bit_cast(float, v);
}
__device__ __forceinline__ u16 f2bf(float f) {
  unsigned u = __builtin_bit_cast(unsigned, f);
  u += 0x7FFFu + ((u >> 16) & 1u);
  return (u16)(u >> 16);
}
__device__ __forceinline__ float fexp2(float x) {   // 2^x, single v_exp_f32
  float r; asm("v_exp_f32 %0, %1" : "=v"(r) : "v"(x)); return r;
}
__device__ __forceinline__ void gload16(const void* g, void* l) {
  __builtin_amdgcn_global_load_lds((const __attribute__((address_space(1))) void*)g,
                                   (__attribute__((address_space(3))) void*)l, 16, 0, 0);
}
#define MFMA16(a, b, c) __builtin_amdgcn_mfma_f32_16x16x32_bf16(a, b, c, 0, 0, 0)

// ---------------- prep kernels ----------------

// f32 [R][C] -> bf16 [C][R]
__global__ void transpose_cast(const float* __restrict__ in, u16* __restrict__ out,
                               int R, int C) {
  __shared__ float t[32][33];
  const int c0 = blockIdx.x * 32, r0 = blockIdx.y * 32;
  const int tx = threadIdx.x, ty = threadIdx.y;
#pragma unroll
  for (int i = 0; i < 4; ++i)
    t[ty + i * 8][tx] = in[(size_t)(r0 + ty + i * 8) * C + c0 + tx];
  __syncthreads();
#pragma unroll
  for (int i = 0; i < 4; ++i)
    out[(size_t)(c0 + ty + i * 8) * R + r0 + tx] = f2bf(t[tx][ty + i * 8]);
}

struct u16x4s { u16 x, y, z, w; };

__global__ void cast_bf16_k(const float* __restrict__ in, u16* __restrict__ out, int n4) {
  int i = blockIdx.x * 256 + threadIdx.x;
  if (i < n4) {
    float4 v = ((const float4*)in)[i];
    u16x4s o;
    o.x = f2bf(v.x); o.y = f2bf(v.y); o.z = f2bf(v.z); o.w = f2bf(v.w);
    ((u16x4s*)out)[i] = o;
  }
}

__global__ void rope_table_k(const int* __restrict__ pos, float* __restrict__ cs,
                             float* __restrict__ sn) {
  int idx = blockIdx.x * 256 + threadIdx.x;   // S_LEN*64 total
  int s = idx >> 6, d = idx & 63;
  float inv = exp2f((-(float)d / 64.f) * 13.287712379549449f); // log2(10000)
  float ang = (float)pos[s] * inv;
  cs[idx] = cosf(ang);
  sn[idx] = sinf(ang);
}

// ---------------- 256x256 4-phase GEMM (16x16x32, R5 schedule, x2-unrolled) --------
// EPI=0: plain f32 output (O-projection).
// EPI=1: fused QKV epilogue via slot-swizzled LDS tile (R13-proven).
// R16: compile-time buffer index (address folding). R17: STAGE issued at the
// TOP of each phase, before the ds_reads (T3 recipe: "issue STAGE before
// ds_read+MFMA") — starts the VMEM prefetch ~1 phase earlier; no hazard
// change (same regions/barriers/waitcnts).
template <int EPI>
__global__ __launch_bounds__(512) void gemm256(
    const u16* __restrict__ A, const u16* __restrict__ Bt,
    const float* __restrict__ bias, void* __restrict__ Cv,
    int M, int N, int K, int nbm,
    u16* __restrict__ Qo, u16* __restrict__ Ko, u16* __restrict__ Vo,
    const float* __restrict__ cs, const float* __restrict__ sn) {
  __shared__ alignas(16) u16 lds[2][2][2][128 * 64];
  const int tid = threadIdx.x;
  const int cpx = gridDim.x >> 3;
  const int swz = (blockIdx.x & 7) * cpx + (blockIdx.x >> 3);   // bijective (nb%8==0)
  const int bm = (swz % nbm) * 256, bn = (swz / nbm) * 256;     // bm fastest: B reuse in L2
  const int w = tid >> 6, l = tid & 63;
  const int wm = w >> 2, wn = w & 3;
  const int lr = l & 15, lg = l >> 4;
  const int rswz = (lr & 7) * 8;                  // read-side XOR (u16 units)
  const int rl = tid >> 3;                        // staging row (per 8 threads)
  const int sl = (tid & 7) ^ ((tid >> 3) & 7);    // staging source slot (inverse swz)
  const u16* Ap = A + (size_t)bm * K;
  const u16* Bp = Bt + (size_t)bn * K;

#define STG(buf, ab, half, kt) do { \
    const u16* s_ = (ab ? Bp : Ap) + (size_t)((half) * 128 + rl) * K + (kt) * 64 + sl * 8; \
    u16* d_ = &lds[buf][ab][half][tid * 8]; \
    gload16(s_, d_); \
    gload16(s_ + (size_t)64 * K, d_ + 4096); \
  } while (0)

  f32x4 acc[8][4] = {};
  // prologue: K-tile 0 complete + K-tile 1 A halves = 12 loads
  STG(0, 0, 0, 0); STG(0, 0, 1, 0); STG(0, 1, 0, 0); STG(0, 1, 1, 0);
  STG(1, 0, 0, 1); STG(1, 0, 1, 1);
  asm volatile("s_waitcnt vmcnt(4)" ::: "memory");   // K-tile 0 landed
  __builtin_amdgcn_s_barrier();

  const int NT = K >> 6;
  bf16x8 alo[4][2], ahi[4][2], bfr[2][2];

  // One K-tile with compile-time BUF; STAGE first in every phase.
#define KTILE(BUF, t) do { \
    const u16* Al = &lds[BUF][0][wm][0]; \
    const u16* Bl = &lds[BUF][1][wn >> 1][0]; \
    const int brow = (wn & 1) * 64; \
    /* ---------- phase 1 ---------- */ \
    if ((t) + 1 < NT) STG(BUF ^ 1, 1, 0, (t) + 1); \
    _Pragma("unroll") for (int mi = 0; mi < 4; ++mi) \
      _Pragma("unroll") for (int ks = 0; ks < 2; ++ks) \
        alo[mi][ks] = *(const bf16x8*)&Al[(mi * 16 + lr) * 64 + ((ks * 32 + lg * 8) ^ rswz)]; \
    _Pragma("unroll") for (int ni = 0; ni < 2; ++ni) \
      _Pragma("unroll") for (int ks = 0; ks < 2; ++ks) \
        bfr[ni][ks] = *(const bf16x8*)&Bl[(brow + ni * 16 + lr) * 64 + ((ks * 32 + lg * 8) ^ rswz)]; \
    __builtin_amdgcn_s_barrier(); \
    __builtin_amdgcn_s_setprio(1); \
    _Pragma("unroll") for (int mi = 0; mi < 4; ++mi) \
      _Pragma("unroll") for (int ni = 0; ni < 2; ++ni) \
        _Pragma("unroll") for (int ks = 0; ks < 2; ++ks) \
          acc[mi][ni] = MFMA16(alo[mi][ks], bfr[ni][ks], acc[mi][ni]); \
    __builtin_amdgcn_s_setprio(0); \
    __builtin_amdgcn_s_barrier(); \
    /* ---------- phase 2 ---------- */ \
    if ((t) + 1 < NT) STG(BUF ^ 1, 1, 1, (t) + 1); \
    _Pragma("unroll") for (int mi = 0; mi < 4; ++mi) \
      _Pragma("unroll") for (int ks = 0; ks < 2; ++ks) \
        ahi[mi][ks] = *(const bf16x8*)&Al[((mi + 4) * 16 + lr) * 64 + ((ks * 32 + lg * 8) ^ rswz)]; \
    __builtin_amdgcn_s_barrier(); \
    __builtin_amdgcn_s_setprio(1); \
    _Pragma("unroll") for (int mi = 0; mi < 4; ++mi) \
      _Pragma("unroll") for (int ni = 0; ni < 2; ++ni) \
        _Pragma("unroll") for (int ks = 0; ks < 2; ++ks) \
          acc[mi + 4][ni] = MFMA16(ahi[mi][ks], bfr[ni][ks], acc[mi + 4][ni]); \
    __builtin_amdgcn_s_setprio(0); \
    __builtin_amdgcn_s_barrier(); \
    /* ---------- phase 3 ---------- */ \
    if ((t) + 2 < NT) STG(BUF, 0, 0, (t) + 2); \
    _Pragma("unroll") for (int ni = 0; ni < 2; ++ni) \
      _Pragma("unroll") for (int ks = 0; ks < 2; ++ks) \
        bfr[ni][ks] = *(const bf16x8*)&Bl[(brow + (ni + 2) * 16 + lr) * 64 + ((ks * 32 + lg * 8) ^ rswz)]; \
    __builtin_amdgcn_s_barrier(); \
    __builtin_amdgcn_s_setprio(1); \
    _Pragma("unroll") for (int mi = 0; mi < 4; ++mi) \
      _Pragma("unroll") for (int ni = 0; ni < 2; ++ni) \
        _Pragma("unroll") for (int ks = 0; ks < 2; ++ks) \
          acc[mi][ni + 2] = MFMA16(alo[mi][ks], bfr[ni][ks], acc[mi][ni + 2]); \
    __builtin_amdgcn_s_setprio(0); \
    __builtin_amdgcn_s_barrier(); \
    /* ---------- phase 4 ---------- */ \
    if ((t) + 2 < NT) { \
      STG(BUF, 0, 1, (t) + 2); \
      asm volatile("s_waitcnt vmcnt(4)" ::: "memory");  /* tile t+1 landed */ \
    } else { \
      asm volatile("s_waitcnt vmcnt(0)" ::: "memory"); \
    } \
    __builtin_amdgcn_s_barrier(); \
    __builtin_amdgcn_s_setprio(1); \
    _Pragma("unroll") for (int mi = 0; mi < 4; ++mi) \
      _Pragma("unroll") for (int ni = 0; ni < 2; ++ni) \
        _Pragma("unroll") for (int ks = 0; ks < 2; ++ks) \
          acc[mi + 4][ni + 2] = MFMA16(ahi[mi][ks], bfr[ni][ks], acc[mi + 4][ni + 2]); \
    __builtin_amdgcn_s_setprio(0); \
    __builtin_amdgcn_s_barrier(); \
  } while (0)

  for (int t = 0; t < NT; t += 2) {   // NT even (K=4096 -> 64)
    KTILE(0, t);
    KTILE(1, t + 1);
  }
#undef KTILE
#undef STG

  if (EPI == 0) {
#pragma unroll
    for (int ni = 0; ni < 4; ++ni) {
      const int col = bn + wn * 64 + ni * 16 + lr;
      const float bv = bias[col];
#pragma unroll
      for (int mi = 0; mi < 8; ++mi) {
        const int row = bm + wm * 128 + mi * 16 + lg * 4;
#pragma unroll
        for (int r = 0; r < 4; ++r)
          ((float*)Cv)[(size_t)(row + r) * N + col] = acc[mi][ni][r] + bv;
      }
    }
  } else {
    // ---- fused QKV epilogue (slot-swizzled tile) ----
    u16* tile = (u16*)lds;          // 256x256 bf16 = 128 KiB (K-loop buffers dead)
    const int cr = lg * 4, cc = lr;
#pragma unroll
    for (int ni = 0; ni < 4; ++ni) {
      const int lcol = wn * 64 + ni * 16 + cc;
      const float bv = bias[bn + lcol];
#pragma unroll
      for (int mi = 0; mi < 8; ++mi) {
        const int lrow = wm * 128 + mi * 16 + cr;
#pragma unroll
        for (int r = 0; r < 4; ++r) {
          const int rw = lrow + r;
          tile[rw * 256 + ((((lcol >> 3) ^ (rw & 7)) << 3) | (lcol & 7))] =
              f2bf(acc[mi][ni][r] + bv);
        }
      }
    }
    __syncthreads();
    if (bn < 2 * HIDN) {
      // Q or K tile: rope pairs (d, d+64) same-thread via LDS
      const float sc = (bn < HIDN) ? 0.12751743f : 1.0f;  // (1/sqrt(128))*log2e in Q
      u16* dst0 = (bn < HIDN) ? Qo : Ko;
      const int hbase = (bn & (HIDN - 1)) >> 7;
#pragma unroll
      for (int it = 0; it < 8; ++it) {
        const int idx = it * 512 + tid;                   // 2 heads*256 s*8 chunks
        const int hh = idx >> 11, slc = (idx >> 3) & 255, d0 = (idx & 7) * 8;
        const int colA = hh * 128 + d0, colB = colA + 64;
        const bf16x8 va = *(const bf16x8*)&tile[slc * 256 + (((colA >> 3) ^ (slc & 7)) << 3)];
        const bf16x8 vb = *(const bf16x8*)&tile[slc * 256 + (((colB >> 3) ^ (slc & 7)) << 3)];
        const int sg = bm + slc, b_ = sg >> 11, s_ = sg & 2047;
        const float4 c0 = *(const float4*)&cs[s_ * 64 + d0];
        const float4 c1 = *(const float4*)&cs[s_ * 64 + d0 + 4];
        const float4 s0v = *(const float4*)&sn[s_ * 64 + d0];
        const float4 s1v = *(const float4*)&sn[s_ * 64 + d0 + 4];
        bf16x8 r1, r2;
#pragma unroll
        for (int j = 0; j < 8; ++j) {
          float x1 = (float)va[j], x2 = (float)vb[j];
          float cj = (j < 4) ? c0[j & 3] : c1[j & 3];
          float sj = (j < 4) ? s0v[j & 3] : s1v[j & 3];
          r1[j] = (__bf16)((x1 * cj - x2 * sj) * sc);
          r2[j] = (__bf16)((x2 * cj + x1 * sj) * sc);
        }
        u16* dp = dst0 + ((size_t)(b_ * NH + hbase + hh) * S_LEN + s_) * HD + d0;
        *(bf16x8*)dp = r1;
        *(bf16x8*)(dp + 64) = r2;
      }
    } else {
      // V tile: transpose to Vt[B,H,D,S]
      const int hbase = (bn - 2 * HIDN) >> 7;
#pragma unroll
      for (int it = 0; it < 16; ++it) {
        const int idx = it * 512 + tid;                   // 32 s-chunks * 256 cols
        const int sc8 = idx >> 8, cl = idx & 255;
        const int s0 = sc8 * 8;
        bf16x8 v;
#pragma unroll
        for (int j = 0; j < 8; ++j) {
          const int rw = s0 + j;
          v[j] = __builtin_bit_cast(__bf16,
                 tile[rw * 256 + ((((cl >> 3) ^ (rw & 7)) << 3) | (cl & 7))]);
        }
        const int sg = bm + s0, b_ = sg >> 11, s_ = sg & 2047;
        const int h_ = hbase + (cl >> 7), d_ = cl & 127;
        *(bf16x8*)&Vo[((size_t)(b_ * NH + h_) * HD + d_) * S_LEN + s_] = v;
      }
    }
  }
}

// ---------------- causal flash attention: 8 waves/block, QBLK=128 (R13) ----------
__global__ __launch_bounds__(512) void attn_k(
    const u16* __restrict__ Q, const u16* __restrict__ K,
    const u16* __restrict__ Vt, u16* __restrict__ O) {
  __shared__ alignas(16) u16 kbuf[2][64 * 128];
  __shared__ alignas(16) u16 vbuf[2][128 * 64];
  __shared__ alignas(16) u16 plds[8][16 * 64];
  const int blk = blockIdx.x;
  const int qb = 15 - (blk >> 6);          // longest blocks dispatch first
  const int bhid = blk & 63;
  const int b = bhid >> 5, h = bhid & 31;
  const int tid = threadIdx.x;
  const int w = tid >> 6, l = tid & 63;
  const int lr = l & 15, lg = l >> 4;
  const size_t bh = (size_t)(b * NH + h);
  const u16* Qp = Q + (bh * S_LEN + (size_t)qb * 128 + (size_t)w * 16) * HD;
  const u16* Kp = K + bh * S_LEN * HD;
  const u16* Vp = Vt + bh * HD * S_LEN;

  bf16x8 qf[4];
#pragma unroll
  for (int kd = 0; kd < 4; ++kd)
    qf[kd] = *(const bf16x8*)&Qp[lr * HD + kd * 32 + lg * 8];

  f32x4 oacc[8] = {};
  float m[4], lsum[4];
#pragma unroll
  for (int r = 0; r < 4; ++r) { m[r] = -1e30f; lsum[r] = 0.f; }
  const int nsteps = 2 * qb + 2;
  const int qmin = qb * 128 + w * 16;      // wave-uniform first q row
  const int qmaxw = qmin + 15;
  const int qrow0 = qmin + lg * 4;

#define ASTAGE(buf, kv0) do { \
    _Pragma("unroll") \
    for (int c = 0; c < 2; ++c) { \
      const int kr = c * 32 + (tid >> 4); \
      const int kc = ((tid & 15) * 8) ^ ((kr & 7) << 3); \
      gload16(Kp + (size_t)((kv0) + kr) * HD + kc, &kbuf[buf][c * 4096 + tid * 8]); \
      const int vr = c * 64 + (tid >> 3); \
      const int vc = ((tid & 7) * 8) ^ ((vr & 7) << 3); \
      gload16(Vp + (size_t)vr * S_LEN + (kv0) + vc, &vbuf[buf][c * 4096 + tid * 8]); \
    } \
  } while (0)

  ASTAGE(0, 0);
  for (int st = 0; st < nsteps; ++st) {
    const int kv0 = st * 64;
    const int cur = st & 1;
    __syncthreads();                       // stage(cur) landed; buf cur^1 free
    if (st + 1 < nsteps) ASTAGE(cur ^ 1, kv0 + 64);

    if (kv0 <= qmaxw) {                    // wave-uniform: skip fully-masked steps
      const int na0 = ((qmaxw - kv0) >> 4) + 1;
      const int na = na0 > 4 ? 4 : na0;    // active 16-col n-blocks (wave-uniform)

      // ---- QK^T (active n-blocks only) ----
      f32x4 sacc[4] = {};
      __builtin_amdgcn_s_setprio(1);
#pragma unroll
      for (int n = 0; n < 4; ++n) {
        if (n < na) {
          const int krow = n * 16 + lr;
          const int swzk = (krow & 7) << 3;
#pragma unroll
          for (int kd = 0; kd < 4; ++kd) {
            const bf16x8 kf = *(const bf16x8*)&kbuf[cur][krow * 128 + ((kd * 32 + lg * 8) ^ swzk)];
            sacc[n] = MFMA16(qf[kd], kf, sacc[n]);
          }
        }
      }
      __builtin_amdgcn_s_setprio(0);
      // ---- causal mask (skip when step fully below diagonal) ----
      float sv[4][4];
      if (kv0 + 63 <= qmin) {
#pragma unroll
        for (int n = 0; n < 4; ++n)
#pragma unroll
          for (int r = 0; r < 4; ++r) sv[n][r] = sacc[n][r];
      } else {
#pragma unroll
        for (int n = 0; n < 4; ++n) {
          const int col = kv0 + n * 16 + lr;
#pragma unroll
          for (int r = 0; r < 4; ++r)
            sv[n][r] = (col <= qrow0 + r) ? sacc[n][r] : -1e30f;
        }
      }
      // ---- row max + defer-max (THR=8 in exp2 domain) ----
      float vmx[4];
#pragma unroll
      for (int r = 0; r < 4; ++r) {
        float v = fmaxf(fmaxf(sv[0][r], sv[1][r]), fmaxf(sv[2][r], sv[3][r]));
#pragma unroll
        for (int off = 1; off < 16; off <<= 1)
          v = fmaxf(v, __shfl_xor(v, off, 16));
        vmx[r] = v;
      }
      bool ok = true;
#pragma unroll
      for (int r = 0; r < 4; ++r) ok &= (vmx[r] <= m[r] + 8.f);
      if (!__all(ok)) {
        float al[4];
#pragma unroll
        for (int r = 0; r < 4; ++r) {
          float mn = fmaxf(m[r], vmx[r]);
          al[r] = fexp2(m[r] - mn);
          m[r] = mn;
          lsum[r] *= al[r];
        }
#pragma unroll
        for (int db = 0; db < 8; ++db)
#pragma unroll
          for (int r = 0; r < 4; ++r)
            oacc[db][r] *= al[r];
      }
      // ---- P = 2^(sv-m), write to LDS, row-sum ----
#pragma unroll
      for (int r = 0; r < 4; ++r) {
        const int prow = lg * 4 + r;
        const int pswz = (prow & 7) << 3;
        float ps = 0.f;
#pragma unroll
        for (int n = 0; n < 4; ++n) {
          float p = fexp2(sv[n][r] - m[r]);
          plds[w][prow * 64 + ((n * 16 + lr) ^ pswz)] = f2bf(p);
          ps += p;
        }
#pragma unroll
        for (int off = 1; off < 16; off <<= 1)
          ps += __shfl_xor(ps, off, 16);
        lsum[r] += ps;
      }
      // ---- PV (skip fully-masked 32-col halves) ----
      __builtin_amdgcn_s_setprio(1);
#pragma unroll
      for (int ks = 0; ks < 2; ++ks) {
        if (kv0 + ks * 32 > qmaxw) continue;   // wave-uniform, P==0 there
        const bf16x8 pf = *(const bf16x8*)&plds[w][lr * 64 + ((ks * 32 + lg * 8) ^ ((lr & 7) << 3))];
#pragma unroll
        for (int db = 0; db < 8; ++db) {
          const int vrow = db * 16 + lr;
          const bf16x8 vf = *(const bf16x8*)&vbuf[cur][vrow * 64 + ((ks * 32 + lg * 8) ^ ((vrow & 7) << 3))];
          oacc[db] = MFMA16(pf, vf, oacc[db]);
        }
      }
      __builtin_amdgcn_s_setprio(0);
    }
  }
#undef ASTAGE

  u16* Op = O + ((size_t)b * S_LEN + (size_t)qb * 128 + (size_t)w * 16) * HIDN + h * HD;
#pragma unroll
  for (int db = 0; db < 8; ++db)
#pragma unroll
    for (int r = 0; r < 4; ++r)
      Op[(size_t)(lg * 4 + r) * HIDN + db * 16 + lr] = f2bf(oacc[db][r] / lsum[r]);
}

// ---------------- launcher ----------------
extern "C" void kernel_launch(void* const* d_in, const int* in_sizes, int n_in,
                              void* d_out, int out_size, void* d_ws, size_t ws_size,
                              hipStream_t stream) {
  const int*   positions = (const int*)d_in[0];
  const float* hidden    = (const float*)d_in[1];
  const float* Wqkv      = (const float*)d_in[2];
  const float* bqkv      = (const float*)d_in[3];
  const float* Wo        = (const float*)d_in[4];
  const float* bo        = (const float*)d_in[5];
  float* out = (float*)d_out;
  char* ws = (char*)d_ws;

  // workspace layout (bytes)
  u16*   WqkvT = (u16*)(ws + 0);            // [12288][4096] bf16, 96 MiB
  u16*   WoT   = (u16*)(ws + 100663296);    // [4096][4096] bf16, 32 MiB
  u16*   Xb    = (u16*)(ws + 134217728);    // [4096][4096] bf16, 32 MiB
  float* cosT  = (float*)(ws + 167772160);  // [2048][64] f32
  float* sinT  = (float*)(ws + 168296448);
  // Q/K/Vt written directly by GEMM1's fused epilogue
  u16* Qr  = (u16*)(ws + 168820736);        // 32 MiB
  u16* Kr  = Qr + 16777216;                 // 32 MiB
  u16* Vtr = Kr + 16777216;                 // 32 MiB
  u16* Ob  = Xb;                            // Xb dead after GEMM1

  transpose_cast<<<dim3(384, 128), dim3(32, 8), 0, stream>>>(Wqkv, WqkvT, 4096, 12288);
  transpose_cast<<<dim3(128, 128), dim3(32, 8), 0, stream>>>(Wo, WoT, 4096, 4096);
  cast_bf16_k<<<16384, 256, 0, stream>>>(hidden, Xb, 4194304);
  rope_table_k<<<512, 256, 0, stream>>>(positions, cosT, sinT);
  gemm256<1><<<768, 512, 0, stream>>>(Xb, WqkvT, bqkv, nullptr, 4096, 12288, 4096, 16,
                                      Qr, Kr, Vtr, cosT, sinT);
  attn_k<<<1024, 512, 0, stream>>>(Qr, Kr, Vtr, Ob);
  gemm256<0><<<256, 512, 0, stream>>>(Ob, WoT, bo, out, 4096, 4096, 4096, 16,
                                      nullptr, nullptr, nullptr, nullptr, nullptr);
}